// Round 1
// baseline (102.450 us; speedup 1.0000x reference)
//
#include <hip/hip_runtime.h>

constexpr int B = 256, N = 512, T = 200, TM1 = 199;
constexpr int SLOTS = (TM1 + 3) / 4;  // 50 slots of 4 j's per (b,n) row
constexpr float MIN_HL = 15.0f / (24.0f * 60.0f);
constexpr float MAX_HL = 274.0f;
constexpr float INV_SPD = 1.0f / 86400.0f;

__device__ __forceinline__ float hl_of(float s0, float s1, float s2,
                                       float th0, float th1, float th2) {
    float logit = fmaf(s0, th0, fmaf(s1, th1, s2 * th2));
    return fminf(fmaxf(exp2f(logit), MIN_HL), MAX_HL);
}

__device__ __forceinline__ float p_of(float hl, float dt_days) {
    float z = exp2f(-dt_days / hl);
    // sigmoid(z) = 1 / (1 + exp(-z)); z in (0,1] so well-conditioned
    return 1.0f / (1.0f + __expf(-z));
}

__global__ __launch_bounds__(256) void hlr_main(
    const float* __restrict__ x0,
    const float* __restrict__ t,
    const float* __restrict__ stats,
    const float* __restrict__ theta,
    float* __restrict__ x_pred,     // (B*N, T)
    float* __restrict__ half_life)  // (B*N, TM1)
{
    const unsigned idx = blockIdx.x * 256u + threadIdx.x;
    const unsigned row = idx / SLOTS;          // b*N + n
    if (row >= (unsigned)(B * N)) return;
    const unsigned slot = idx - row * SLOTS;
    const unsigned b = row >> 9;               // N = 512
    const int j0 = slot * 4;

    const float th0 = theta[0], th1 = theta[1], th2 = theta[2];

    // 48 B of stats for 4 j's: row base is 2400 B (16B aligned), j0*12 B with j0%4==0 -> aligned
    const float4* sp = reinterpret_cast<const float4*>(
        stats + (size_t)row * (T * 3) + (size_t)j0 * 3);
    const float4 sA = sp[0];
    const float4 sB = sp[1];
    const float4 sC = sp[2];

    const float* trow = t + (size_t)b * T;
    const float t0 = trow[j0];
    const float t1 = trow[j0 + 1];
    const float t2 = trow[j0 + 2];
    const float t3 = trow[j0 + 3];                       // j0+3 <= 199 always
    const float t4 = (j0 + 4 < T) ? trow[j0 + 4] : 0.f;  // only needed when j0+3 < TM1

    // per-j stats triplets:
    // j0  : sA.x sA.y sA.z
    // j0+1: sA.w sB.x sB.y
    // j0+2: sB.z sB.w sC.x
    // j0+3: sC.y sC.z sC.w
    const float hl0 = hl_of(sA.x, sA.y, sA.z, th0, th1, th2);
    const float hl1 = hl_of(sA.w, sB.x, sB.y, th0, th1, th2);
    const float hl2 = hl_of(sB.z, sB.w, sC.x, th0, th1, th2);
    const float hl3 = hl_of(sC.y, sC.z, sC.w, th0, th1, th2);

    const float p0 = p_of(hl0, (t1 - t0) * INV_SPD);
    const float p1 = p_of(hl1, (t2 - t1) * INV_SPD);
    const float p2 = p_of(hl2, (t3 - t2) * INV_SPD);
    const float p3 = p_of(hl3, (t4 - t3) * INV_SPD);

    float* xp = x_pred + (size_t)row * T;
    float* hp = half_life + (size_t)row * TM1;

    if (slot == 0) xp[0] = x0[row];

    // j0..j0+2 always valid (j0 <= 196 -> j0+2 <= 198); j0+3 valid unless last slot
    xp[j0 + 1] = p0;  hp[j0]     = hl0;
    xp[j0 + 2] = p1;  hp[j0 + 1] = hl1;
    xp[j0 + 3] = p2;  hp[j0 + 2] = hl2;
    if (j0 + 3 < TM1) { xp[j0 + 4] = p3; hp[j0 + 3] = hl3; }
}

__global__ __launch_bounds__(256) void hlr_item(
    const float* __restrict__ t,
    const int* __restrict__ items,
    const float* __restrict__ stats,
    const float* __restrict__ theta,
    float* __restrict__ x_item)  // (B, TM1)
{
    const int i = blockIdx.x * 256 + threadIdx.x;
    if (i >= B * TM1) return;
    const int b = i / TM1;
    const int j = i - b * TM1;
    const int n = items[(size_t)b * T + j + 1];

    const float th0 = theta[0], th1 = theta[1], th2 = theta[2];
    const float* s = stats + ((size_t)(b * N + n) * T + j) * 3;
    const float hl = hl_of(s[0], s[1], s[2], th0, th1, th2);
    const float dt = (t[(size_t)b * T + j + 1] - t[(size_t)b * T + j]) * INV_SPD;
    x_item[i] = p_of(hl, dt);
}

extern "C" void kernel_launch(void* const* d_in, const int* in_sizes, int n_in,
                              void* d_out, int out_size, void* d_ws, size_t ws_size,
                              hipStream_t stream) {
    const float* x0    = (const float*)d_in[0];
    const float* t     = (const float*)d_in[1];
    const int*   items = (const int*)d_in[2];
    const float* stats = (const float*)d_in[3];
    const float* theta = (const float*)d_in[4];

    float* out = (float*)d_out;
    float* x_pred    = out;                                   // B*N*T
    float* x_item    = out + (size_t)B * N * T;               // B*TM1
    float* half_life = out + (size_t)B * N * T + (size_t)B * TM1;  // B*N*TM1

    {
        const unsigned total = (unsigned)(B * N) * SLOTS;     // 6,553,600
        const unsigned blocks = (total + 255) / 256;          // 25,600
        hlr_main<<<blocks, 256, 0, stream>>>(x0, t, stats, theta, x_pred, half_life);
    }
    {
        const int total = B * TM1;                            // 50,944
        const int blocks = (total + 255) / 256;
        hlr_item<<<blocks, 256, 0, stream>>>(t, items, stats, theta, x_item);
    }
}